// Round 2
// baseline (190.992 us; speedup 1.0000x reference)
//
#include <hip/hip_runtime.h>
#include <hip/hip_bf16.h>

#define NB 16
#define NC 4
#define NL 4096
#define NK 256
#define NS 128
#define NW (NL - NS + 1)   /* 3969 */
#define NWT 63             /* ceil(NW/64) window tiles */
#define EPSF 1e-8f

typedef __attribute__((ext_vector_type(8))) short bf16x8;
typedef __attribute__((ext_vector_type(4))) float floatx4;

__device__ inline short f2bf(float f) {
    __hip_bfloat16 h = __float2bfloat16(f);
    short s;
    __builtin_memcpy(&s, &h, sizeof(short));
    return s;
}

// K1: normalize shapelets (fp32 in), write bf16 bits. One wave per (c,k).
__global__ __launch_bounds__(64)
void norm_shp_kernel(const float* __restrict__ shp, short* __restrict__ shpn) {
    int ck = blockIdx.x;            // c*NK + k, 0..1023
    int lane = threadIdx.x;         // 0..63
    const float* p = shp + (size_t)ck * NS;
    float v0 = p[lane];
    float v1 = p[lane + 64];
    float ss = v0 * v0 + v1 * v1;
    #pragma unroll
    for (int o = 32; o > 0; o >>= 1) ss += __shfl_xor(ss, o, 64);
    float rn = 1.f / fmaxf(sqrtf(ss), EPSF);
    shpn[(size_t)ck * NS + lane]      = f2bf(v0 * rn);
    shpn[(size_t)ck * NS + lane + 64] = f2bf(v1 * rn);
}

// K2: sliding-window inverse norms (fp32). Block = (window-quarter, b*c row).
__global__ __launch_bounds__(256)
void win_inv_kernel(const float* __restrict__ x, float* __restrict__ inv) {
    __shared__ float xr[1024 + NS];     // 1152 floats
    int wq  = blockIdx.x;               // 0..3
    int bc  = blockIdx.y;               // 0..63
    int tid = threadIdx.x;
    int base = wq * 1024;
    const float* p = x + (size_t)bc * NL;
    for (int i = tid; i < 1024 + NS; i += 256) {
        int g = base + i;
        xr[i] = (g < NL) ? p[g] : 0.f;
    }
    __syncthreads();
    float acc[4] = {0.f, 0.f, 0.f, 0.f};
    for (int s = 0; s < NS; s++) {
        #pragma unroll
        for (int i = 0; i < 4; i++) {
            float v = xr[tid + 256 * i + s];
            acc[i] += v * v;
        }
    }
    #pragma unroll
    for (int i = 0; i < 4; i++) {
        int w = base + tid + 256 * i;
        if (w < NW) inv[(size_t)bc * NW + w] = 1.f / fmaxf(sqrtf(acc[i]), EPSF);
    }
}

// K3: main MFMA kernel. Block = (wtile, b); 4 waves x 16 windows x 256 K.
__global__ __launch_bounds__(256, 2)
void mcs_main_kernel(const float* __restrict__ x,
                     const short* __restrict__ shpn,
                     const float* __restrict__ inv,
                     float* __restrict__ partial) {
    __shared__ float xs[NC][192];
    __shared__ float invs[NC][64];
    __shared__ float red[4][NK];

    int wt = blockIdx.x, b = blockIdx.y;
    int w0 = wt * 64;
    int tid = threadIdx.x;

    // Stage x: indices w0 .. w0+191 per channel (windows share!)
    for (int i = tid; i < NC * 192; i += 256) {
        int c = i / 192, o = i % 192;
        int g = w0 + o;
        xs[c][o] = (g < NL) ? x[((size_t)b * NC + c) * NL + g] : 0.f;
    }
    { // Stage inverse norms for this tile's 64 windows; 0 for invalid tail.
        int c = tid >> 6, o = tid & 63;
        int w = w0 + o;
        invs[c][o] = (w < NW) ? inv[((size_t)b * NC + c) * NW + w] : 0.f;
    }
    __syncthreads();

    int wv = tid >> 6, lane = tid & 63;
    int m = lane & 15, q = lane >> 4;
    int wr = wv * 16 + m;               // block-local window row for A frag

    floatx4 acc[16];
    #pragma unroll
    for (int t = 0; t < 16; t++) acc[t] = (floatx4){0.f, 0.f, 0.f, 0.f};

    for (int c = 0; c < NC; c++) {
        float im = invs[c][wr];
        const float* xrow = &xs[c][wr];         // xrow[s] = window element s
        #pragma unroll
        for (int s0 = 0; s0 < NS; s0 += 32) {
            bf16x8 a;
            #pragma unroll
            for (int j = 0; j < 8; j++)
                a[j] = f2bf(xrow[s0 + q * 8 + j] * im);
            const short* bp = shpn + (size_t)c * NK * NS + s0 + q * 8;
            #pragma unroll
            for (int t = 0; t < 16; t++) {
                bf16x8 bfrag = *reinterpret_cast<const bf16x8*>(bp + (size_t)(t * 16 + m) * NS);
                acc[t] = __builtin_amdgcn_mfma_f32_16x16x32_bf16(a, bfrag, acc[t], 0, 0, 0);
            }
        }
    }

    // Max over the wave's 16 window rows (D: col=lane&15, row=quad*4+reg).
    #pragma unroll
    for (int t = 0; t < 16; t++) {
        floatx4 v = acc[t];
        float mx = fmaxf(fmaxf(v.x, v.y), fmaxf(v.z, v.w));
        mx = fmaxf(mx, __shfl_xor(mx, 16, 64));
        mx = fmaxf(mx, __shfl_xor(mx, 32, 64));
        if (lane < 16) red[wv][t * 16 + lane] = mx;
    }
    __syncthreads();
    if (tid < NK) {
        float p0 = fmaxf(fmaxf(red[0][tid], red[1][tid]), fmaxf(red[2][tid], red[3][tid]));
        partial[((size_t)b * NWT + wt) * NK + tid] = p0;
    }
}

// K4: reduce over window tiles, apply 1/C scale + ReLU (mx init 0), emit fp32.
__global__ __launch_bounds__(256)
void finalize_kernel(const float* __restrict__ partial, float* __restrict__ out) {
    int b = blockIdx.x, k = threadIdx.x;
    float mx = 0.f;
    for (int wt = 0; wt < NWT; wt++)
        mx = fmaxf(mx, partial[((size_t)b * NWT + wt) * NK + k]);
    out[(size_t)b * NK + k] = 0.25f * mx;
}

extern "C" void kernel_launch(void* const* d_in, const int* in_sizes, int n_in,
                              void* d_out, int out_size, void* d_ws, size_t ws_size,
                              hipStream_t stream) {
    (void)in_sizes; (void)n_in; (void)out_size; (void)ws_size;
    const float* x   = (const float*)d_in[0];
    const float* shp = (const float*)d_in[1];
    float* out = (float*)d_out;

    char* ws = (char*)d_ws;
    short* shpn    = (short*)ws;                                   // 262144 B
    float* inv     = (float*)(ws + 262144);                        // 1016064 B
    float* partial = (float*)(ws + 262144 + 1016064);              // 1032192 B

    norm_shp_kernel<<<NC * NK, 64, 0, stream>>>(shp, shpn);
    win_inv_kernel<<<dim3(4, NB * NC), 256, 0, stream>>>(x, inv);
    mcs_main_kernel<<<dim3(NWT, NB), 256, 0, stream>>>(x, shpn, inv, partial);
    finalize_kernel<<<NB, 256, 0, stream>>>(partial, out);
}

// Round 3
// 79.973 us; speedup vs baseline: 2.3882x; 2.3882x over previous
//
#include <hip/hip_runtime.h>
#include <hip/hip_bf16.h>

#define NB 16
#define NC 4
#define NL 4096
#define NK 256
#define NS 128
#define NW (NL - NS + 1)          /* 3969 */
#define WPB 128                   /* windows per block */
#define NWT ((NW + WPB - 1) / WPB) /* 32 window tiles */
#define EPSF 1e-8f

typedef __attribute__((ext_vector_type(8))) short bf16x8;
typedef __attribute__((ext_vector_type(4))) float floatx4;

__device__ inline short f2bf(float f) {
    __hip_bfloat16 h = __float2bfloat16(f);
    short s;
    __builtin_memcpy(&s, &h, sizeof(short));
    return s;
}

// K1: normalize shapelets (fp32 in), write bf16 bits. One wave per (c,k).
__global__ __launch_bounds__(64)
void norm_shp_kernel(const float* __restrict__ shp, short* __restrict__ shpn) {
    int ck = blockIdx.x;            // c*NK + k
    int lane = threadIdx.x;
    const float* p = shp + (size_t)ck * NS;
    float v0 = p[lane];
    float v1 = p[lane + 64];
    float ss = v0 * v0 + v1 * v1;
    #pragma unroll
    for (int o = 32; o > 0; o >>= 1) ss += __shfl_xor(ss, o, 64);
    float rn = 1.f / fmaxf(sqrtf(ss), EPSF);
    shpn[(size_t)ck * NS + lane]      = f2bf(v0 * rn);
    shpn[(size_t)ck * NS + lane + 64] = f2bf(v1 * rn);
}

// K3: fused main kernel. Block = (wtile, b); 4 waves, 128 windows, 256 k.
// B staged per-c in swizzled LDS; window inv-norms computed in-block.
__global__ __launch_bounds__(256, 2)
void mcs_main_kernel(const float* __restrict__ x,
                     const short* __restrict__ shpn,
                     float* __restrict__ partial) {
    __shared__ bf16x8 bs[NK * 16];          // 64 KB: one channel's B, swizzled
    __shared__ float xs[NC][WPB + NS];      // 4 KB
    __shared__ float invs[NC][WPB];         // 2 KB
    __shared__ float red[4][NK];            // 4 KB

    const int wt = blockIdx.x, b = blockIdx.y;
    const int w0 = wt * WPB;
    const int tid = threadIdx.x;

    // ---- issue x loads (regs) ----
    float xv[4];
    #pragma unroll
    for (int i = 0; i < 4; i++) {
        int idx = tid + 256 * i;            // 0..1023
        int c = idx >> 8, o = idx & 255;
        int g = w0 + o;
        xv[i] = (g < NL) ? x[((size_t)b * NC + c) * NL + g] : 0.f;
    }
    // ---- issue B(c=0) loads (regs, fly during norm compute) ----
    bf16x8 breg[16];
    {
        const bf16x8* p = (const bf16x8*)shpn;
        #pragma unroll
        for (int i = 0; i < 16; i++) breg[i] = p[i * 256 + tid];
    }
    // ---- store xs ----
    #pragma unroll
    for (int i = 0; i < 4; i++) {
        int idx = tid + 256 * i;
        xs[idx >> 8][idx & 255] = xv[i];
    }
    __syncthreads();
    // ---- window inverse norms (2 per thread) ----
    #pragma unroll
    for (int i = 0; i < 2; i++) {
        int idx = tid + 256 * i;            // 0..511
        int c = idx >> 7, o = idx & 127;
        const float* p = &xs[c][o];
        float ss = 0.f;
        #pragma unroll 4
        for (int s = 0; s < NS; s++) { float v = p[s]; ss += v * v; }
        int w = w0 + o;
        invs[c][o] = (w < NW) ? 1.f / fmaxf(sqrtf(ss), EPSF) : 0.f;
    }
    // ---- write B(c=0) to swizzled LDS ----
    #pragma unroll
    for (int i = 0; i < 16; i++) {
        int g = i * 256 + tid;              // global 16B-chunk id
        int k = g >> 4, cc = g & 15;
        bs[(k << 4) | (cc ^ (k & 15))] = breg[i];
    }
    __syncthreads();

    const int lane = tid & 63, wv = tid >> 6;
    const int m = lane & 15, q = lane >> 4;

    floatx4 acc[2][16];
    #pragma unroll
    for (int mt = 0; mt < 2; mt++)
        #pragma unroll
        for (int t = 0; t < 16; t++) acc[mt][t] = (floatx4){0.f, 0.f, 0.f, 0.f};

    for (int c = 0; c < NC; c++) {
        if (c < NC - 1) {   // prefetch next channel's B into regs (in flight during MFMA)
            const bf16x8* p = (const bf16x8*)(shpn + (size_t)(c + 1) * NK * NS);
            #pragma unroll
            for (int i = 0; i < 16; i++) breg[i] = p[i * 256 + tid];
        }
        const float im0 = invs[c][wv * 32 + m];
        const float im1 = invs[c][wv * 32 + 16 + m];
        const float* xr0 = &xs[c][wv * 32 + m];
        #pragma unroll
        for (int s0 = 0; s0 < NS; s0 += 32) {
            bf16x8 a0, a1;
            #pragma unroll
            for (int j = 0; j < 8; j++) {
                a0[j] = f2bf(xr0[s0 + q * 8 + j] * im0);
                a1[j] = f2bf(xr0[16 + s0 + q * 8 + j] * im1);
            }
            const int base = (m << 4) | (((s0 >> 3) + q) ^ m);
            #pragma unroll
            for (int t = 0; t < 16; t++) {
                bf16x8 bf = bs[t * 256 + base];
                acc[0][t] = __builtin_amdgcn_mfma_f32_16x16x32_bf16(a0, bf, acc[0][t], 0, 0, 0);
                acc[1][t] = __builtin_amdgcn_mfma_f32_16x16x32_bf16(a1, bf, acc[1][t], 0, 0, 0);
            }
        }
        if (c < NC - 1) {
            __syncthreads();                 // all waves done reading bs for c
            #pragma unroll
            for (int i = 0; i < 16; i++) {
                int g = i * 256 + tid;
                int k = g >> 4, cc = g & 15;
                bs[(k << 4) | (cc ^ (k & 15))] = breg[i];
            }
            __syncthreads();                 // bs ready for c+1
        }
    }

    // Max over this wave's 32 windows (D: col=lane&15, row=quad*4+reg).
    #pragma unroll
    for (int t = 0; t < 16; t++) {
        floatx4 v0 = acc[0][t], v1 = acc[1][t];
        float mx = fmaxf(fmaxf(fmaxf(v0.x, v0.y), fmaxf(v0.z, v0.w)),
                         fmaxf(fmaxf(v1.x, v1.y), fmaxf(v1.z, v1.w)));
        mx = fmaxf(mx, __shfl_xor(mx, 16, 64));
        mx = fmaxf(mx, __shfl_xor(mx, 32, 64));
        if (lane < 16) red[wv][t * 16 + lane] = mx;
    }
    __syncthreads();
    if (tid < NK) {
        float p0 = fmaxf(fmaxf(red[0][tid], red[1][tid]), fmaxf(red[2][tid], red[3][tid]));
        partial[((size_t)b * NWT + wt) * NK + tid] = p0;
    }
}

// K4: reduce over window tiles, apply 1/C scale + ReLU (mx init 0), emit fp32.
__global__ __launch_bounds__(256)
void finalize_kernel(const float* __restrict__ partial, float* __restrict__ out) {
    int b = blockIdx.x, k = threadIdx.x;
    float mx = 0.f;
    for (int wtile = 0; wtile < NWT; wtile++)
        mx = fmaxf(mx, partial[((size_t)b * NWT + wtile) * NK + k]);
    out[(size_t)b * NK + k] = 0.25f * mx;
}

extern "C" void kernel_launch(void* const* d_in, const int* in_sizes, int n_in,
                              void* d_out, int out_size, void* d_ws, size_t ws_size,
                              hipStream_t stream) {
    (void)in_sizes; (void)n_in; (void)out_size; (void)ws_size;
    const float* x   = (const float*)d_in[0];
    const float* shp = (const float*)d_in[1];
    float* out = (float*)d_out;

    char* ws = (char*)d_ws;
    short* shpn    = (short*)ws;                    // 262144 B
    float* partial = (float*)(ws + 262144);         // 16*32*256*4 = 524288 B

    norm_shp_kernel<<<NC * NK, 64, 0, stream>>>(shp, shpn);
    mcs_main_kernel<<<dim3(NWT, NB), 256, 0, stream>>>(x, shpn, partial);
    finalize_kernel<<<NB, 256, 0, stream>>>(partial, out);
}

// Round 4
// 79.972 us; speedup vs baseline: 2.3882x; 1.0000x over previous
//
#include <hip/hip_runtime.h>
#include <hip/hip_bf16.h>

#define NB 16
#define NC 4
#define NL 4096
#define NK 256
#define NS 128
#define NW (NL - NS + 1)           /* 3969 */
#define WPB 128                    /* windows per block */
#define NWT ((NW + WPB - 1) / WPB) /* 32 window tiles */
#define EPSF 1e-8f

typedef __attribute__((ext_vector_type(8))) short bf16x8;
typedef __attribute__((ext_vector_type(4))) float floatx4;

__device__ inline short f2bf(float f) {
    __hip_bfloat16 h = __float2bfloat16(f);
    short s;
    __builtin_memcpy(&s, &h, sizeof(short));
    return s;
}

// K1: normalize shapelets (fp32 in), write bf16 bits. One wave per (c,k).
__global__ __launch_bounds__(64)
void norm_shp_kernel(const float* __restrict__ shp, short* __restrict__ shpn) {
    int ck = blockIdx.x;
    int lane = threadIdx.x;
    const float* p = shp + (size_t)ck * NS;
    float v0 = p[lane];
    float v1 = p[lane + 64];
    float ss = v0 * v0 + v1 * v1;
    #pragma unroll
    for (int o = 32; o > 0; o >>= 1) ss += __shfl_xor(ss, o, 64);
    float rn = 1.f / fmaxf(sqrtf(ss), EPSF);
    shpn[(size_t)ck * NS + lane]      = f2bf(v0 * rn);
    shpn[(size_t)ck * NS + lane + 64] = f2bf(v1 * rn);
}

// K2: main kernel. Block = (wtile, b); wave wv: windows (wv>>1)*64..+63,
// k-half (wv&1)*128..+127. Scan-based norms, aligned A via 4 shift-copies,
// swizzled B in LDS, atomicMax epilogue (no finalize kernel).
__global__ __launch_bounds__(256, 2)
void mcs_main_kernel(const float* __restrict__ x,
                     const short* __restrict__ shpn,
                     float* __restrict__ out) {
    __shared__ bf16x8 bs[NK * 16];                       // 64 KB, swizzled B
    __shared__ alignas(16) short xcp[NC][4][264];        // 8.25 KB shifted bf16 x
    __shared__ alignas(16) float scratch[NC][264];       // x^2 -> prefix P -> red
    __shared__ float invs[NC][WPB];                      // 2 KB

    const int wt = blockIdx.x, b = blockIdx.y;
    const int w0 = wt * WPB;
    const int tid = threadIdx.x;
    const int lane = tid & 63, wv = tid >> 6;

    // ---- stage x: thread tid holds element o=tid of each channel ----
    float xv[NC];
    #pragma unroll
    for (int c = 0; c < NC; c++) {
        int g = w0 + tid;
        xv[c] = (g < NL) ? x[((size_t)b * NC + c) * NL + g] : 0.f;
    }
    // ---- B(c=0) prefetch into regs ----
    bf16x8 breg[16];
    {
        const bf16x8* p = (const bf16x8*)shpn;
        #pragma unroll
        for (int i = 0; i < 16; i++) breg[i] = p[i * 256 + tid];
    }
    // ---- write shift-copies (bf16) + squares ----
    #pragma unroll
    for (int c = 0; c < NC; c++) {
        short hv = f2bf(xv[c]);
        #pragma unroll
        for (int r = 0; r < 4; r++) {
            int o2 = tid - r;
            if (o2 >= 0) xcp[c][r][o2] = hv;
        }
        scratch[c][tid] = xv[c] * xv[c];
    }
    __syncthreads();

    // ---- in-place inclusive prefix scan: wave wv scans channel wv ----
    {
        float4 v = *(const float4*)&scratch[wv][lane * 4];
        v.y += v.x; v.z += v.y; v.w += v.z;
        float tot = v.w;
        #pragma unroll
        for (int o = 1; o < 64; o <<= 1) {
            float u = __shfl_up(tot, o, 64);
            if (lane >= o) tot += u;
        }
        float excl = tot - v.w;
        v.x += excl; v.y += excl; v.z += excl; v.w += excl;
        *(float4*)&scratch[wv][lane * 4] = v;
    }
    // ---- write B(c=0) swizzled ----
    #pragma unroll
    for (int i = 0; i < 16; i++) {
        int g = i * 256 + tid;
        int k = g >> 4, cc = g & 15;
        bs[(k << 4) | (cc ^ (k & 15))] = breg[i];
    }
    __syncthreads();

    // ---- window inverse norms from prefix sums (2 per thread) ----
    #pragma unroll
    for (int i = 0; i < 2; i++) {
        int idx = tid + 256 * i;
        int c = idx >> 7, o = idx & 127;
        float nn = scratch[c][o + 127] - (o ? scratch[c][o - 1] : 0.f);
        int w = w0 + o;
        invs[c][o] = (w < NW) ? 1.f / fmaxf(sqrtf(fmaxf(nn, 0.f)), EPSF) : 0.f;
    }
    __syncthreads();

    const int m = lane & 15, q = lane >> 4;
    const int kh = wv & 1, wh = wv >> 1;

    floatx4 acc[4][8];
    #pragma unroll
    for (int mt = 0; mt < 4; mt++)
        #pragma unroll
        for (int kt = 0; kt < 8; kt++) acc[mt][kt] = (floatx4){0.f, 0.f, 0.f, 0.f};

    const int r = m & 3;
    for (int c = 0; c < NC; c++) {
        if (c < NC - 1) {   // prefetch next channel's B (in flight over MFMA)
            const bf16x8* p = (const bf16x8*)(shpn + (size_t)(c + 1) * NK * NS);
            #pragma unroll
            for (int i = 0; i < 16; i++) breg[i] = p[i * 256 + tid];
        }
        float im[4];
        #pragma unroll
        for (int mt = 0; mt < 4; mt++) im[mt] = invs[c][wh * 64 + mt * 16 + m];

        #pragma unroll
        for (int s0 = 0; s0 < NS; s0 += 32) {
            bf16x8 a[4];
            #pragma unroll
            for (int mt = 0; mt < 4; mt++) {
                int tt = wh * 64 + mt * 16 + m + s0 + q * 8;   // start element
                const uint2* pp = (const uint2*)&xcp[c][r][tt - r];
                uint2 u0 = pp[0], u1 = pp[1];
                float imv = im[mt];
                a[mt][0] = f2bf(__uint_as_float(u0.x << 16) * imv);
                a[mt][1] = f2bf(__uint_as_float(u0.x & 0xffff0000u) * imv);
                a[mt][2] = f2bf(__uint_as_float(u0.y << 16) * imv);
                a[mt][3] = f2bf(__uint_as_float(u0.y & 0xffff0000u) * imv);
                a[mt][4] = f2bf(__uint_as_float(u1.x << 16) * imv);
                a[mt][5] = f2bf(__uint_as_float(u1.x & 0xffff0000u) * imv);
                a[mt][6] = f2bf(__uint_as_float(u1.y << 16) * imv);
                a[mt][7] = f2bf(__uint_as_float(u1.y & 0xffff0000u) * imv);
            }
            int cc = (s0 >> 3) + q;
            #pragma unroll
            for (int kt = 0; kt < 8; kt++) {
                int k = kh * 128 + kt * 16 + m;
                bf16x8 bf = bs[(k << 4) | (cc ^ m)];
                #pragma unroll
                for (int mt = 0; mt < 4; mt++)
                    acc[mt][kt] = __builtin_amdgcn_mfma_f32_16x16x32_bf16(a[mt], bf, acc[mt][kt], 0, 0, 0);
            }
        }
        if (c < NC - 1) {
            __syncthreads();
            #pragma unroll
            for (int i = 0; i < 16; i++) {
                int g = i * 256 + tid;
                int k = g >> 4, cc = g & 15;
                bs[(k << 4) | (cc ^ (k & 15))] = breg[i];
            }
            __syncthreads();
        }
    }

    // ---- epilogue: max over this wave's 64 windows per k, then atomicMax ----
    __syncthreads();   // scratch reused as red[wv][128]
    #pragma unroll
    for (int kt = 0; kt < 8; kt++) {
        floatx4 v0 = acc[0][kt], v1 = acc[1][kt], v2 = acc[2][kt], v3 = acc[3][kt];
        float mx = fmaxf(fmaxf(fmaxf(v0.x, v0.y), fmaxf(v0.z, v0.w)),
                         fmaxf(fmaxf(v1.x, v1.y), fmaxf(v1.z, v1.w)));
        mx = fmaxf(mx, fmaxf(fmaxf(fmaxf(v2.x, v2.y), fmaxf(v2.z, v2.w)),
                             fmaxf(fmaxf(v3.x, v3.y), fmaxf(v3.z, v3.w))));
        mx = fmaxf(mx, __shfl_xor(mx, 16, 64));
        mx = fmaxf(mx, __shfl_xor(mx, 32, 64));
        if (lane < 16) scratch[wv][kt * 16 + lane] = mx;
    }
    __syncthreads();
    {
        int k = tid;
        int khh = k >> 7, lk = k & 127;
        float v = fmaxf(scratch[khh][lk], scratch[khh + 2][lk]);
        v = fmaxf(v, 0.f) * 0.25f;    // ReLU + 1/C, nonneg -> int-monotonic
        atomicMax((int*)out + (size_t)b * NK + k, __float_as_int(v));
    }
}

extern "C" void kernel_launch(void* const* d_in, const int* in_sizes, int n_in,
                              void* d_out, int out_size, void* d_ws, size_t ws_size,
                              hipStream_t stream) {
    (void)in_sizes; (void)n_in; (void)out_size; (void)ws_size;
    const float* x   = (const float*)d_in[0];
    const float* shp = (const float*)d_in[1];
    float* out = (float*)d_out;

    short* shpn = (short*)d_ws;     // 256 KB of workspace

    norm_shp_kernel<<<NC * NK, 64, 0, stream>>>(shp, shpn);
    mcs_main_kernel<<<dim3(NWT, NB), 256, 0, stream>>>(x, shpn, out);
}